// Round 1
// baseline (718.535 us; speedup 1.0000x reference)
//
#include <hip/hip_runtime.h>

typedef short bf16x8 __attribute__((ext_vector_type(8)));
typedef float f32x4 __attribute__((ext_vector_type(4)));

__device__ inline float bf2f(unsigned short s){ union{unsigned u; float f;} x; x.u=((unsigned)s)<<16; return x.f; }
__device__ inline unsigned short f2bf(float f){ union{float f; unsigned u;} x; x.f=f; unsigned r = x.u + 0x7fff + ((x.u>>16)&1u); return (unsigned short)(r>>16); }

// ---------------- setup kernels ----------------
__global__ void k_hist(const int* __restrict__ dstA, int* __restrict__ cnt, int E){
    int e = blockIdx.x*256 + threadIdx.x;
    if(e < E) atomicAdd(&cnt[dstA[e]], 1);
}

__global__ void k_dinv(const int* __restrict__ cnt, float* __restrict__ dinv, int n){
    int i = blockIdx.x*256 + threadIdx.x;
    if(i < n) dinv[i] = rsqrtf((float)(cnt[i] + 1));   // +1 self loop
}

__global__ void k_scan1(const int* __restrict__ cnt, int* __restrict__ tmp, int* __restrict__ bsum, int n){
    __shared__ int s[1024];
    int i = blockIdx.x*1024 + threadIdx.x;
    int v = (i < n) ? cnt[i] : 0;
    s[threadIdx.x] = v; __syncthreads();
    for(int off=1; off<1024; off<<=1){
        int t = (threadIdx.x >= off) ? s[threadIdx.x-off] : 0;
        __syncthreads();
        s[threadIdx.x] += t;
        __syncthreads();
    }
    if(i < n) tmp[i] = s[threadIdx.x];
    if(threadIdx.x == 1023) bsum[blockIdx.x] = s[1023];
}

__global__ void k_scan2(int* bsum, int nb){
    if(blockIdx.x==0 && threadIdx.x==0){
        int acc = 0;
        for(int i=0;i<nb;i++){ int t = bsum[i]; bsum[i] = acc; acc += t; }
    }
}

__global__ void k_scan3(const int* __restrict__ tmp, const int* __restrict__ bsum, int* __restrict__ rowptr, int n){
    int i = blockIdx.x*256 + threadIdx.x;
    if(i < n){
        rowptr[i+1] = tmp[i] + bsum[i>>10];
        if(i == 0) rowptr[0] = 0;
    }
}

__global__ void k_fill(const int* __restrict__ srcA, const int* __restrict__ dstA,
                       const int* __restrict__ rowptr, int* __restrict__ cursor,
                       const float* __restrict__ dinv, int* __restrict__ col, float* __restrict__ ew, int E){
    int e = blockIdx.x*256 + threadIdx.x;
    if(e < E){
        int d = dstA[e], s = srcA[e];
        int slot = atomicAdd(&cursor[d], 1);
        int j = rowptr[d] + slot;
        col[j] = s;
        ew[j] = dinv[s];
    }
}

__global__ void k_cvt(const float4* __restrict__ in, ushort4* __restrict__ out, int n4){
    int i = blockIdx.x*256 + threadIdx.x;
    if(i < n4){
        float4 v = in[i];
        out[i] = make_ushort4(f2bf(v.x), f2bf(v.y), f2bf(v.z), f2bf(v.w));
    }
}

// transpose W [k][n] -> Wt [n][k] in bf16, all 3 layers
__global__ void k_prep_w(const float* __restrict__ W0, const float* __restrict__ W1, const float* __restrict__ W2,
                         unsigned short* __restrict__ Wt){
    int idx = blockIdx.x*256 + threadIdx.x;
    if(idx >= 3*65536) return;
    int l = idx >> 16, rem = idx & 65535;
    int k = rem >> 8, n = rem & 255;
    const float* W = (l==0) ? W0 : ((l==1) ? W1 : W2);
    Wt[l*65536 + n*256 + k] = f2bf(W[k*256 + n]);
}

__global__ void k_pad(float4* __restrict__ out4, int total, int G){
    int i = blockIdx.x*256 + threadIdx.x;
    if(i >= total) return;
    int rowsPad = 512 - G;
    int per = rowsPad * 192;
    int g = i / per; int rem = i - g*per;
    int r = rem / 192, c = rem - r*192;
    out4[((size_t)(g*512 + G + r))*192 + c] = make_float4(0.f,0.f,0.f,0.f);
}

// ---------------- GEMM: y[N,256] = hb[N,256] @ W[256,256]  (bf16 in, bf16 out) ----------------
__global__ __launch_bounds__(256) void k_gemm(const uint4* __restrict__ A4,   // hb as [M][32] 16B chunks
                                              const uint4* __restrict__ B4,   // Wt  as [256][32] chunks (row n, k contiguous)
                                              unsigned short* __restrict__ Y, int M){
    __shared__ uint4 smA[1024];   // 128 rows x 64 bf16 (swizzled)
    __shared__ uint4 smB[1024];
    const int tid  = threadIdx.x;
    const int lane = tid & 63;
    const int w    = tid >> 6;
    const int wr   = w >> 1, wc = w & 1;
    const int r15  = lane & 15, hi = lane >> 4;
    const int rowBase = blockIdx.x * 128;
    const int colBase = blockIdx.y * 128;

    f32x4 acc[4][4] = {};
    char* pA = (char*)smA;
    char* pB = (char*)smB;

    for(int kt=0; kt<4; ++kt){
        const int kc0 = kt*8;
        #pragma unroll
        for(int it=0; it<4; ++it){
            int cs  = (it<<8) + tid;        // 0..1023
            int row = cs >> 3, ch = cs & 7;
            int swz = ((ch ^ (row & 7)) << 4);
            int grow = rowBase + row;
            uint4 va = make_uint4(0,0,0,0);
            if(grow < M) va = A4[(size_t)grow*32 + kc0 + ch];
            *(uint4*)(pA + (row<<7) + swz) = va;
            int brow = colBase + row;
            uint4 vb = B4[(size_t)brow*32 + kc0 + ch];
            *(uint4*)(pB + (row<<7) + swz) = vb;
        }
        __syncthreads();
        #pragma unroll
        for(int kk=0; kk<2; ++kk){
            const int kbyte = kk*64 + hi*16;
            bf16x8 fa[4], fb[4];
            #pragma unroll
            for(int m=0;m<4;++m){
                int lrow = wr*64 + m*16 + r15;
                fa[m] = *(const bf16x8*)(pA + (lrow<<7) + (kbyte ^ ((lrow&7)<<4)));
            }
            #pragma unroll
            for(int nn=0;nn<4;++nn){
                int lcol = wc*64 + nn*16 + r15;
                fb[nn] = *(const bf16x8*)(pB + (lcol<<7) + (kbyte ^ ((lcol&7)<<4)));
            }
            #pragma unroll
            for(int m=0;m<4;++m)
                #pragma unroll
                for(int nn=0;nn<4;++nn)
                    acc[m][nn] = __builtin_amdgcn_mfma_f32_16x16x32_bf16(fa[m], fb[nn], acc[m][nn], 0,0,0);
        }
        __syncthreads();
    }
    #pragma unroll
    for(int m=0;m<4;++m){
        int growb = rowBase + wr*64 + m*16 + hi*4;
        #pragma unroll
        for(int nn=0;nn<4;++nn){
            int gcol = colBase + wc*64 + nn*16 + r15;
            #pragma unroll
            for(int r=0;r<4;++r){
                int grow = growb + r;
                if(grow < M) Y[(size_t)grow*256 + gcol] = f2bf(acc[m][nn][r]);
            }
        }
    }
}

// ---------------- aggregation: z[i] = dinv[i]*(sum_e dinv[src]*y[src] + dinv[i]*y[i]) ----------------
__global__ __launch_bounds__(256) void k_aggregate(const ushort4* __restrict__ yb,
                                                   const int* __restrict__ rowptr,
                                                   const int* __restrict__ col,
                                                   const float* __restrict__ ew,
                                                   const float* __restrict__ dinv,
                                                   float4* __restrict__ z, int n){
    int wid = (blockIdx.x<<2) + (threadIdx.x>>6);
    if(wid >= n) return;
    int lane = threadIdx.x & 63;
    float di = dinv[wid];
    ushort4 sv = yb[(size_t)wid*64 + lane];
    float a0 = di*bf2f(sv.x), a1 = di*bf2f(sv.y), a2 = di*bf2f(sv.z), a3 = di*bf2f(sv.w);
    float b0 = 0.f, b1 = 0.f, b2 = 0.f, b3 = 0.f;
    int j = rowptr[wid], end = rowptr[wid+1];
    for(; j+1 < end; j += 2){
        int c0 = col[j], c1 = col[j+1];
        float w0 = ew[j], w1 = ew[j+1];
        ushort4 v0 = yb[(size_t)c0*64 + lane];
        ushort4 v1 = yb[(size_t)c1*64 + lane];
        a0 += w0*bf2f(v0.x); a1 += w0*bf2f(v0.y); a2 += w0*bf2f(v0.z); a3 += w0*bf2f(v0.w);
        b0 += w1*bf2f(v1.x); b1 += w1*bf2f(v1.y); b2 += w1*bf2f(v1.z); b3 += w1*bf2f(v1.w);
    }
    if(j < end){
        int c0 = col[j]; float w0 = ew[j];
        ushort4 v0 = yb[(size_t)c0*64 + lane];
        a0 += w0*bf2f(v0.x); a1 += w0*bf2f(v0.y); a2 += w0*bf2f(v0.z); a3 += w0*bf2f(v0.w);
    }
    float4 o;
    o.x = di*(a0+b0); o.y = di*(a1+b1); o.z = di*(a2+b2); o.w = di*(a3+b3);
    z[(size_t)wid*64 + lane] = o;
}

// ---------------- BN stats ----------------
__global__ __launch_bounds__(256) void k_stats(const float4* __restrict__ z4, float* __restrict__ sum, float* __restrict__ sumsq, int n){
    int q = threadIdx.x & 63;
    int r = blockIdx.x*4 + (threadIdx.x>>6);
    float sx=0,sy=0,sz=0,sw=0, qx=0,qy=0,qz=0,qw=0;
    for(; r < n; r += gridDim.x*4){
        float4 v = z4[(size_t)r*64 + q];
        sx += v.x; sy += v.y; sz += v.z; sw += v.w;
        qx += v.x*v.x; qy += v.y*v.y; qz += v.z*v.z; qw += v.w*v.w;
    }
    atomicAdd(&sum[q*4+0], sx); atomicAdd(&sum[q*4+1], sy);
    atomicAdd(&sum[q*4+2], sz); atomicAdd(&sum[q*4+3], sw);
    atomicAdd(&sumsq[q*4+0], qx); atomicAdd(&sumsq[q*4+1], qy);
    atomicAdd(&sumsq[q*4+2], qz); atomicAdd(&sumsq[q*4+3], qw);
}

__global__ void k_finalize(const float* __restrict__ sum, const float* __restrict__ sumsq,
                           const float* __restrict__ gamma, const float* __restrict__ beta,
                           float* __restrict__ a, float* __restrict__ bb, int n){
    int c = threadIdx.x;
    float inv = 1.0f / (float)n;
    float mu  = sum[c]*inv;
    float var = sumsq[c]*inv - mu*mu;
    float s   = gamma[c]*rsqrtf(var + 1e-5f);
    a[c]  = s;
    bb[c] = beta[c] - mu*s;
}

// ---------------- BN+ReLU + next-layer bf16 + dense-batch output write ----------------
__global__ __launch_bounds__(256) void k_bnrelu(const float4* __restrict__ z4, const float* __restrict__ a, const float* __restrict__ bb,
                                                ushort4* __restrict__ hb_out, float4* __restrict__ out4, int layer, int n4, int G){
    int idx = blockIdx.x*256 + threadIdx.x;
    if(idx >= n4) return;
    int node = idx >> 6, q = idx & 63;
    float4 v = z4[idx];
    float4 A  = ((const float4*)a)[q];
    float4 Bv = ((const float4*)bb)[q];
    float4 r;
    r.x = fmaxf(fmaf(v.x, A.x, Bv.x), 0.f);
    r.y = fmaxf(fmaf(v.y, A.y, Bv.y), 0.f);
    r.z = fmaxf(fmaf(v.z, A.z, Bv.z), 0.f);
    r.w = fmaxf(fmaf(v.w, A.w, Bv.w), 0.f);
    if(hb_out) hb_out[idx] = make_ushort4(f2bf(r.x), f2bf(r.y), f2bf(r.z), f2bf(r.w));
    int g = node / G;
    int p = node - g*G;
    out4[((size_t)(g*512 + p))*192 + layer*64 + q] = r;
}

extern "C" void kernel_launch(void* const* d_in, const int* in_sizes, int n_in,
                              void* d_out, int out_size, void* d_ws, size_t ws_size,
                              hipStream_t stream){
    const int F = 256;
    const int N = in_sizes[0] / F;      // 50000
    const int E = in_sizes[1] / 2;      // 800000
    const int Bg = 100;
    const int G = N / Bg;               // 500

    const float* x  = (const float*)d_in[0];
    const int*   ei = (const int*)d_in[1];
    const float* Wp[3]  = {(const float*)d_in[4],  (const float*)d_in[8],  (const float*)d_in[12]};
    const float* gam[3] = {(const float*)d_in[6],  (const float*)d_in[10], (const float*)d_in[14]};
    const float* bet[3] = {(const float*)d_in[7],  (const float*)d_in[11], (const float*)d_in[15]};
    float* out = (float*)d_out;

    char* wp = (char*)d_ws;
    auto alloc = [&](size_t b)->char*{ char* p = wp; wp += ((b + 255)/256)*256; return p; };
    int*   cnt    = (int*)  alloc((size_t)N*4);
    int*   cursor = (int*)  alloc((size_t)N*4);
    int*   rowptr = (int*)  alloc((size_t)(N+1)*4);
    int*   tmp    = (int*)  alloc((size_t)N*4);
    int*   bsum   = (int*)  alloc(256*4);
    int*   col    = (int*)  alloc((size_t)E*4);
    float* ew     = (float*)alloc((size_t)E*4);
    float* dinv   = (float*)alloc((size_t)N*4);
    float* ssum   = (float*)alloc(256*4);
    float* ssq    = (float*)alloc(256*4);
    float* avec   = (float*)alloc(256*4);
    float* bvec   = (float*)alloc(256*4);
    unsigned short* Wt  = (unsigned short*)alloc(3*65536*2);
    unsigned short* hbA = (unsigned short*)alloc((size_t)N*256*2);
    unsigned short* hbB = (unsigned short*)alloc((size_t)N*256*2);
    unsigned short* ybf = (unsigned short*)alloc((size_t)N*256*2);
    float* z = (float*)alloc((size_t)N*256*4);

    hipMemsetAsync(cnt,    0, (size_t)N*4, stream);
    hipMemsetAsync(cursor, 0, (size_t)N*4, stream);

    const int* srcA = ei;
    const int* dstA = ei + E;
    int gE = (E+255)/256, gN = (N+255)/256;
    k_hist<<<gE,256,0,stream>>>(dstA, cnt, E);
    k_dinv<<<gN,256,0,stream>>>(cnt, dinv, N);
    int nb = (N+1023)/1024;
    k_scan1<<<nb,1024,0,stream>>>(cnt, tmp, bsum, N);
    k_scan2<<<1,1,0,stream>>>(bsum, nb);
    k_scan3<<<gN,256,0,stream>>>(tmp, bsum, rowptr, N);
    k_fill<<<gE,256,0,stream>>>(srcA, dstA, rowptr, cursor, dinv, col, ew, E);

    int n4 = N*64;  // float4 / ushort4 quads per feature map
    k_cvt<<<(n4+255)/256,256,0,stream>>>((const float4*)x, (ushort4*)hbA, n4);
    k_prep_w<<<768,256,0,stream>>>(Wp[0], Wp[1], Wp[2], Wt);
    int padq = Bg*(512-G)*192;
    k_pad<<<(padq+255)/256,256,0,stream>>>((float4*)out, padq, G);

    unsigned short* hin  = hbA;
    unsigned short* hout = hbB;
    dim3 ggrid((N+127)/128, 2);
    for(int l=0; l<3; ++l){
        k_gemm<<<ggrid,256,0,stream>>>((const uint4*)hin, (const uint4*)(Wt + (size_t)l*65536), ybf, N);
        k_aggregate<<<(N+3)/4,256,0,stream>>>((const ushort4*)ybf, rowptr, col, ew, dinv, (float4*)z, N);
        hipMemsetAsync(ssum, 0, 256*4, stream);
        hipMemsetAsync(ssq,  0, 256*4, stream);
        k_stats<<<128,256,0,stream>>>((const float4*)z, ssum, ssq, N);
        k_finalize<<<1,256,0,stream>>>(ssum, ssq, gam[l], bet[l], avec, bvec, N);
        k_bnrelu<<<(n4+255)/256,256,0,stream>>>((const float4*)z, avec, bvec,
                                                (l<2) ? (ushort4*)hout : (ushort4*)nullptr,
                                                (float4*)out, l, n4, G);
        unsigned short* t = hin; hin = hout; hout = t;
    }
}